// Round 9
// baseline (233.302 us; speedup 1.0000x reference)
//
#include <hip/hip_runtime.h>
#include <hip/hip_bf16.h>

typedef __bf16 bf16_t;
typedef __attribute__((ext_vector_type(8))) __bf16 bf16x8;
typedef __attribute__((ext_vector_type(4))) __bf16 bf16x4;
typedef __attribute__((ext_vector_type(4))) short s16x4;
typedef __attribute__((ext_vector_type(4))) float f32x4;
typedef __attribute__((ext_vector_type(4))) _Float16 f16x4;

#define NTOK 4096
#define DIM  768
#define NH   12
#define HD   64
#define NSPLIT 4
#define KHALF (NTOK / NSPLIT)   // 1024 -> NIT=16
#define XSZ  (NTOK * DIM)       // 3,145,728
#define WQSZ (3 * DIM * DIM)    // 1,769,472
#define WPSZ (DIM * DIM)        //   589,824
// 0.125 * log2(e): folded into Q so S^T is directly in log2 domain
#define SCALE_L2E 0.18033688011112042f
// static softmax shift (shift-invariant, no overflow for |st|<~15)
#define SOFTMAX_C 12.0f

__device__ __forceinline__ bf16x8 load8(const bf16_t* p) {
    return *reinterpret_cast<const bf16x8*>(p);
}
__device__ __forceinline__ void store8(bf16_t* p, bf16x8 v) {
    *reinterpret_cast<bf16x8*>(p) = v;
}
// async global->LDS, 16B per lane; LDS dest = wave-uniform base + lane*16
__device__ __forceinline__ void gl2lds16(const bf16_t* g, bf16_t* l) {
    __builtin_amdgcn_global_load_lds(
        (const __attribute__((address_space(1))) void*)g,
        (__attribute__((address_space(3))) void*)l, 16, 0, 0);
}

// ---------------------------------------------------------------------------
// Convert fp32 inputs to bf16 once (memory-bound, ~33 MB total).
// ---------------------------------------------------------------------------
__global__ __launch_bounds__(256) void cvt_kernel(
    const float* __restrict__ x, const float* __restrict__ wq,
    const float* __restrict__ wp,
    bf16_t* __restrict__ xb, bf16_t* __restrict__ wqb, bf16_t* __restrict__ wpb)
{
    size_t i = ((size_t)blockIdx.x * 256 + threadIdx.x) * 4;
    const float* src; bf16_t* dst; size_t off;
    if (i < XSZ)             { src = x;  dst = xb;  off = i; }
    else if (i < XSZ + WQSZ) { src = wq; dst = wqb; off = i - XSZ; }
    else                     { src = wp; dst = wpb; off = i - XSZ - WQSZ; }
    float4 v = *reinterpret_cast<const float4*>(src + off);
    bf16x4 o = { (bf16_t)v.x, (bf16_t)v.y, (bf16_t)v.z, (bf16_t)v.w };
    *reinterpret_cast<bf16x4*>(dst + off) = o;
}

// ---------------------------------------------------------------------------
// QKV GEMM, m97-style: 128x128 tile, BK=32, staging via global_load_lds
// width=16 into CONTIGUOUS [128][32] LDS. 2 barriers per K-step.
// Epilogue scatter: t=0: Q[h][m][d] (*SCALE_L2E)  t=1: K[h][m][d]
//                   t=2: Vt[h][d][m] (8B stores)
// ---------------------------------------------------------------------------
__global__ __launch_bounds__(256) void qkv_gemm_kernel(
    const bf16_t* __restrict__ X, const bf16_t* __restrict__ W,
    bf16_t* __restrict__ Qo, bf16_t* __restrict__ Ko, bf16_t* __restrict__ Vt)
{
    __shared__ __align__(16) bf16_t As[128 * 32];
    __shared__ __align__(16) bf16_t Bs[128 * 32];
    const int tid  = threadIdx.x;
    const int wave = tid >> 6, lane = tid & 63;
    const int lr = lane & 15, lq = lane >> 4;
    const int M0 = blockIdx.x * 128;
    const int N0 = blockIdx.y * 128;
    const int wm = (wave >> 1) * 64, wn = (wave & 1) * 64;

    const int g_row = wave * 32 + (lane >> 2);     // + c*16
    const int g_col = (lane & 3) * 8;

    f32x4 acc[4][4] = {};

    for (int k0 = 0; k0 < DIM; k0 += 32) {
        #pragma unroll
        for (int c = 0; c < 2; ++c) {
            gl2lds16(&X[(size_t)(M0 + g_row + c * 16) * DIM + k0 + g_col],
                     &As[(wave * 32 + c * 16) * 32]);
            gl2lds16(&W[(size_t)(N0 + g_row + c * 16) * DIM + k0 + g_col],
                     &Bs[(wave * 32 + c * 16) * 32]);
        }
        __syncthreads();   // drains vmcnt: LDS tiles complete
        bf16x8 af[4], bfr[4];
        #pragma unroll
        for (int i = 0; i < 4; ++i) af[i]  = load8(&As[(wm + i * 16 + lr) * 32 + lq * 8]);
        #pragma unroll
        for (int i = 0; i < 4; ++i) bfr[i] = load8(&Bs[(wn + i * 16 + lr) * 32 + lq * 8]);
        #pragma unroll
        for (int r = 0; r < 4; ++r)
            #pragma unroll
            for (int c = 0; c < 4; ++c)
                acc[r][c] = __builtin_amdgcn_mfma_f32_16x16x32_bf16(af[r], bfr[c], acc[r][c], 0, 0, 0);
        __syncthreads();   // protect LDS before next overwrite
    }

    const int t = N0 / DIM;      // uniform per block (768 % 128 == 0)
    if (t == 2) {
        #pragma unroll
        for (int r = 0; r < 4; ++r)
            #pragma unroll
            for (int c = 0; c < 4; ++c) {
                int m0 = M0 + wm + r * 16 + lq * 4;
                int rem = N0 + wn + c * 16 + lr - 2 * DIM;
                int hh = rem >> 6, d = rem & 63;
                bf16x4 v = { (bf16_t)acc[r][c][0], (bf16_t)acc[r][c][1],
                             (bf16_t)acc[r][c][2], (bf16_t)acc[r][c][3] };
                *reinterpret_cast<bf16x4*>(&Vt[((size_t)hh * HD + d) * NTOK + m0]) = v;
            }
    } else {
        #pragma unroll
        for (int r = 0; r < 4; ++r)
            #pragma unroll
            for (int c = 0; c < 4; ++c)
                #pragma unroll
                for (int reg = 0; reg < 4; ++reg) {
                    int m = M0 + wm + r * 16 + lq * 4 + reg;
                    int rem = N0 + wn + c * 16 + lr - t * DIM;
                    int hh = rem >> 6, d = rem & 63;
                    float v = acc[r][c][reg];
                    if (t == 0) Qo[(hh * NTOK + m) * HD + d] = (bf16_t)(v * SCALE_L2E);
                    else        Ko[(hh * NTOK + m) * HD + d] = (bf16_t)v;
                }
    }
}

// ---------------------------------------------------------------------------
// Flash attention, S^T form, static-shift softmax, split-K=4.
// *** r9: 4 waves x 64 q-rows/wave (256-thread blocks, 256 q/block). ***
// r8 falsified the barrier-drain theory (counted vmcnt: 80.9 vs 80.0 us).
// Pipe accounting shows flash is LDS-READ-bound: every wave reads the whole
// K tile (8x b128/lane) + V tile (16x b64/lane) = 16KB/wave-iter; at 85B/cy
// that's ~148k cyc + 24k conflict cyc of the 192k wall (~90%). Fragment
// distribution is already minimal, so the only lever is MORE Q PER LDS BYTE:
// 64 q/wave amortizes the same fragment reads over 4 q-subtiles (A,B,C,D).
// Total LDS read traffic HALVES (3072 waves x 16KB vs 6144 x 16KB).
// Cost: ~170 unified regs -> ~3 waves/SIMD = the 3 blocks/CU the grid gives.
//
// Counted-vmcnt skeleton from r8 (proven safe): prologue stages tiles 0+1
// then one __syncthreads; loop = compute(buf) -> lgkmcnt(0)+sbar ->
// stage(it+2, 4 gl2lds) -> vmcnt(4) (tile it+1 done; 4 just-issued in
// flight) -> sbar. Tail drains vmcnt(0).
//
// XOR-swizzled stride-64 LDS: cell (row, swgroup) holds original column
// group swgroup ^ (row&7). Reads: kc0/kc1, vc[g] lane consts. Staging via
// global_load_lds: LDS dest LINEAR; swizzle in per-lane GLOBAL source col
// (wave w covers rows w*16..+16 in 2 calls: srow=lane>>3, src col group
// (lane&7)^srow -- r5-proven 256-thread geometry).
// Softmax row-sum via ones-MFMA (l = ls[0]); QK acc init -SOFTMAX_C.
// NOTE: plain __launch_bounds__(256); (N,waves) hints force arch/acc split
// and spill (r2: 48 VGPR, 432 MB scratch, 242 us).
// ---------------------------------------------------------------------------
__global__ __launch_bounds__(256) void flash_attn_kernel(
    const bf16_t* __restrict__ Qb, const bf16_t* __restrict__ Kb,
    const bf16_t* __restrict__ Vtb, _Float16* __restrict__ Opart,
    float* __restrict__ Lpart)
{
    __shared__ __align__(16) bf16_t Ks[2][64 * 64];   // [key][d]  swizzled
    __shared__ __align__(16) bf16_t Vs[2][64 * 64];   // [d][key]  swizzled
    const int tid  = threadIdx.x;
    const int wave = tid >> 6, lane = tid & 63;       // wave 0..3
    const int lr = lane & 15, lq = lane >> 4;
    const int h  = blockIdx.y;
    const int q0 = blockIdx.x * 256;
    const int sp = blockIdx.z;
    const int kt0 = sp * KHALF;
    const int NIT = KHALF / 64;     // 16

    // read-side swizzle constants (elements) -- unchanged from r3..r8
    const int kc0 = (lq ^ (lr & 7)) * 8;                             // K frag d 0..31
    const int kc1 = ((4 + lq) ^ (lr & 7)) * 8;                       // K frag d 32..63
    int vc[4];
    #pragma unroll
    for (int g = 0; g < 4; ++g)
        vc[g] = ((2 * g + (lq >> 1)) ^ (lr & 7)) * 8 + (lq & 1) * 4; // V frag keys

    // staging (r5-proven): wave w covers rows w*16..w*16+16 in 2 calls
    const int srow = lane >> 3;                        // 0..7
    const int scol = ((lane & 7) ^ srow) * 8;          // inverse-swizzled col
    const bf16_t* kbase = &Kb[(size_t)h * NTOK * HD];
    const bf16_t* vbase = &Vtb[(size_t)h * HD * NTOK];
    const size_t kofA = (size_t)(wave * 16 + srow) * HD + scol;
    const size_t kofB = kofA + (size_t)8 * HD;
    const size_t vofA = (size_t)(wave * 16 + srow) * NTOK + scol;
    const size_t vofB = vofA + (size_t)8 * NTOK;
    const int ldA = (wave * 16) * 64;
    const int ldB = (wave * 16 + 8) * 64;

    // Q as B-operand of S^T for FOUR q-subtiles (rows +lr, +16+lr, +32+lr, +48+lr)
    const bf16_t* qrow = &Qb[((size_t)h * NTOK + q0 + wave * 64 + lr) * HD];
    bf16x8 qa0 = load8(&qrow[lq * 8]);
    bf16x8 qa1 = load8(&qrow[32 + lq * 8]);
    bf16x8 qb0 = load8(&qrow[16 * HD + lq * 8]);
    bf16x8 qb1 = load8(&qrow[16 * HD + 32 + lq * 8]);
    bf16x8 qc0 = load8(&qrow[32 * HD + lq * 8]);
    bf16x8 qc1 = load8(&qrow[32 * HD + 32 + lq * 8]);
    bf16x8 qd0 = load8(&qrow[48 * HD + lq * 8]);
    bf16x8 qd1 = load8(&qrow[48 * HD + 32 + lq * 8]);

    f32x4 oA[4] = {}, oB[4] = {}, oC[4] = {}, oD[4] = {};
    f32x4 lsA = {}, lsB = {}, lsC = {}, lsD = {};   // ones-MFMA row-sum acc
    const f32x4 mc = { -SOFTMAX_C, -SOFTMAX_C, -SOFTMAX_C, -SOFTMAX_C };
    const short ONE = (short)0x3F80;                // bf16 1.0
    const s16x4 ones = { ONE, ONE, ONE, ONE };

    // prologue: stage tiles 0 and 1 (4 gl2lds each), then ONE full drain
    gl2lds16(kbase + (size_t)kt0 * HD + kofA, &Ks[0][ldA]);
    gl2lds16(kbase + (size_t)kt0 * HD + kofB, &Ks[0][ldB]);
    gl2lds16(vbase + kt0 + vofA,              &Vs[0][ldA]);
    gl2lds16(vbase + kt0 + vofB,              &Vs[0][ldB]);
    gl2lds16(kbase + (size_t)(kt0 + 64) * HD + kofA, &Ks[1][ldA]);
    gl2lds16(kbase + (size_t)(kt0 + 64) * HD + kofB, &Ks[1][ldB]);
    gl2lds16(vbase + (kt0 + 64) + vofA,              &Vs[1][ldA]);
    gl2lds16(vbase + (kt0 + 64) + vofB,              &Vs[1][ldB]);
    __syncthreads();                   // tiles 0 AND 1 resident block-wide

    for (int it = 0; it < NIT; ++it) {
        const int buf = it & 1;

        // fused per key-group: QK -> exp2 -> pack -> PV (+ones row-sum)
        #pragma unroll
        for (int g = 0; g < 4; ++g) {
            bf16x8 k0 = load8(&Ks[buf][(g * 16 + lr) * 64 + kc0]);
            bf16x8 k1 = load8(&Ks[buf][(g * 16 + lr) * 64 + kc1]);
            f32x4 za = mc, zb = mc, zc = mc, zd = mc;
            __builtin_amdgcn_s_setprio(1);
            za = __builtin_amdgcn_mfma_f32_16x16x32_bf16(k0, qa0, za, 0, 0, 0);
            za = __builtin_amdgcn_mfma_f32_16x16x32_bf16(k1, qa1, za, 0, 0, 0);
            zb = __builtin_amdgcn_mfma_f32_16x16x32_bf16(k0, qb0, zb, 0, 0, 0);
            zb = __builtin_amdgcn_mfma_f32_16x16x32_bf16(k1, qb1, zb, 0, 0, 0);
            zc = __builtin_amdgcn_mfma_f32_16x16x32_bf16(k0, qc0, zc, 0, 0, 0);
            zc = __builtin_amdgcn_mfma_f32_16x16x32_bf16(k1, qc1, zc, 0, 0, 0);
            zd = __builtin_amdgcn_mfma_f32_16x16x32_bf16(k0, qd0, zd, 0, 0, 0);
            zd = __builtin_amdgcn_mfma_f32_16x16x32_bf16(k1, qd1, zd, 0, 0, 0);
            __builtin_amdgcn_s_setprio(0);
            #pragma unroll
            for (int r = 0; r < 4; ++r) {
                za[r] = __builtin_amdgcn_exp2f(za[r]);
                zb[r] = __builtin_amdgcn_exp2f(zb[r]);
                zc[r] = __builtin_amdgcn_exp2f(zc[r]);
                zd[r] = __builtin_amdgcn_exp2f(zd[r]);
            }
            bf16x4 pa = { (bf16_t)za[0], (bf16_t)za[1], (bf16_t)za[2], (bf16_t)za[3] };
            bf16x4 pb = { (bf16_t)zb[0], (bf16_t)zb[1], (bf16_t)zb[2], (bf16_t)zb[3] };
            bf16x4 pc = { (bf16_t)zc[0], (bf16_t)zc[1], (bf16_t)zc[2], (bf16_t)zc[3] };
            bf16x4 pd = { (bf16_t)zd[0], (bf16_t)zd[1], (bf16_t)zd[2], (bf16_t)zd[3] };
            s16x4 psa = __builtin_bit_cast(s16x4, pa);
            s16x4 psb = __builtin_bit_cast(s16x4, pb);
            s16x4 psc = __builtin_bit_cast(s16x4, pc);
            s16x4 psd = __builtin_bit_cast(s16x4, pd);
            __builtin_amdgcn_s_setprio(1);
            lsA = __builtin_amdgcn_mfma_f32_16x16x16bf16_1k(ones, psa, lsA, 0, 0, 0);
            lsB = __builtin_amdgcn_mfma_f32_16x16x16bf16_1k(ones, psb, lsB, 0, 0, 0);
            lsC = __builtin_amdgcn_mfma_f32_16x16x16bf16_1k(ones, psc, lsC, 0, 0, 0);
            lsD = __builtin_amdgcn_mfma_f32_16x16x16bf16_1k(ones, psd, lsD, 0, 0, 0);
            #pragma unroll
            for (int dt = 0; dt < 4; ++dt) {
                s16x4 va = *reinterpret_cast<const s16x4*>(
                    &Vs[buf][(dt * 16 + lr) * 64 + vc[g]]);
                oA[dt] = __builtin_amdgcn_mfma_f32_16x16x16bf16_1k(va, psa, oA[dt], 0, 0, 0);
                oB[dt] = __builtin_amdgcn_mfma_f32_16x16x16bf16_1k(va, psb, oB[dt], 0, 0, 0);
                oC[dt] = __builtin_amdgcn_mfma_f32_16x16x16bf16_1k(va, psc, oC[dt], 0, 0, 0);
                oD[dt] = __builtin_amdgcn_mfma_f32_16x16x16bf16_1k(va, psd, oD[dt], 0, 0, 0);
            }
            __builtin_amdgcn_s_setprio(0);
        }

        if (it == NIT - 1) break;      // last tile: no restage, no wait

        // my LDS reads retired -> safe for others to overwrite after barrier
        asm volatile("s_waitcnt lgkmcnt(0)" ::: "memory");
        __builtin_amdgcn_sched_barrier(0);
        __builtin_amdgcn_s_barrier();      // all waves done reading buf

        if (it + 2 < NIT) {
            const int kn = kt0 + (it + 2) * 64;
            gl2lds16(kbase + (size_t)kn * HD + kofA, &Ks[buf][ldA]);
            gl2lds16(kbase + (size_t)kn * HD + kofB, &Ks[buf][ldB]);
            gl2lds16(vbase + kn + vofA,              &Vs[buf][ldA]);
            gl2lds16(vbase + kn + vofB,              &Vs[buf][ldB]);
            // tile it+1 complete (only the 4 just-issued stay in flight)
            asm volatile("s_waitcnt vmcnt(4)" ::: "memory");
        } else {
            asm volatile("s_waitcnt vmcnt(0)" ::: "memory");  // tail drain
        }
        __builtin_amdgcn_sched_barrier(0);
        __builtin_amdgcn_s_barrier();      // tile it+1 visible block-wide
    }

    // every C row of the ones-MFMA holds the row-sum for q-col lr
    const int mbase = q0 + wave * 64 + lr;
    if (lq == 0) {
        float* lp = &Lpart[((size_t)sp * NH + h) * NTOK + mbase];
        lp[0]  = lsA[0];
        lp[16] = lsB[0];
        lp[32] = lsC[0];
        lp[48] = lsD[0];
    }
    #pragma unroll
    for (int s = 0; s < 4; ++s) {
        const f32x4* o = (s == 0) ? oA : (s == 1) ? oB : (s == 2) ? oC : oD;
        _Float16* op = &Opart[((size_t)sp * NTOK + mbase + s * 16) * DIM + h * HD];
        #pragma unroll
        for (int dt = 0; dt < 4; ++dt) {
            f16x4 v = { (_Float16)o[dt][0], (_Float16)o[dt][1],
                        (_Float16)o[dt][2], (_Float16)o[dt][3] };
            *reinterpret_cast<f16x4*>(&op[dt * 16 + lq * 4]) = v;
        }
    }
}

// ---------------------------------------------------------------------------
// Split-K combine: one pass over the NSPLIT fp16 partials, normalize by the
// summed softmax denominators, emit bf16 A for the proj GEMM.
// ---------------------------------------------------------------------------
__global__ __launch_bounds__(256) void combine_kernel(
    const _Float16* __restrict__ Opart, const float* __restrict__ Lpart,
    bf16_t* __restrict__ Ab)
{
    int idx = blockIdx.x * 256 + threadIdx.x;       // over NTOK*DIM/4
    int m = idx / (DIM / 4);
    int c = (idx - m * (DIM / 4)) * 4;
    int hh = c >> 6;
    float l = 0.f;
    #pragma unroll
    for (int s = 0; s < NSPLIT; ++s)
        l += Lpart[((size_t)s * NH + hh) * NTOK + m];
    float rv = 1.f / l;
    float a0 = 0.f, a1 = 0.f, a2 = 0.f, a3 = 0.f;
    #pragma unroll
    for (int s = 0; s < NSPLIT; ++s) {
        f16x4 v = *reinterpret_cast<const f16x4*>(
            &Opart[((size_t)s * NTOK + m) * DIM + c]);
        a0 += (float)v[0]; a1 += (float)v[1];
        a2 += (float)v[2]; a3 += (float)v[3];
    }
    bf16x4 o = { (bf16_t)(a0 * rv), (bf16_t)(a1 * rv),
                 (bf16_t)(a2 * rv), (bf16_t)(a3 * rv) };
    *reinterpret_cast<bf16x4*>(&Ab[(size_t)m * DIM + c]) = o;
}

// ---------------------------------------------------------------------------
// Proj GEMM: plain bf16 GEMM out = A @ Wp^T + bias, 64x64 tile, BK=32,
// gl2lds16 staging into contiguous [64][32] LDS (bank-uniform for b128
// frag reads).
// ---------------------------------------------------------------------------
__global__ __launch_bounds__(256) void proj_gemm_kernel(
    const bf16_t* __restrict__ A, const bf16_t* __restrict__ W,
    const float* __restrict__ bias, float* __restrict__ out)
{
    __shared__ __align__(16) bf16_t As[64 * 32];
    __shared__ __align__(16) bf16_t Bs[64 * 32];
    const int tid  = threadIdx.x;
    const int wave = tid >> 6, lane = tid & 63;
    const int lr = lane & 15, lq = lane >> 4;
    const int M0 = blockIdx.x * 64;
    const int N0 = blockIdx.y * 64;
    const int wr = (wave >> 1) * 32, wc = (wave & 1) * 32;
    const int g_row = tid >> 2;           // 0..63
    const int g_col = (tid & 3) * 8;

    f32x4 acc[2][2] = {};

    for (int k0 = 0; k0 < DIM; k0 += 32) {
        gl2lds16(&A[(size_t)(M0 + g_row) * DIM + k0 + g_col], &As[wave * 512]);
        gl2lds16(&W[(size_t)(N0 + g_row) * DIM + k0 + g_col], &Bs[wave * 512]);
        __syncthreads();
        bf16x8 a0 = load8(&As[(wr + lr) * 32 + lq * 8]);
        bf16x8 a1 = load8(&As[(wr + 16 + lr) * 32 + lq * 8]);
        bf16x8 b0 = load8(&Bs[(wc + lr) * 32 + lq * 8]);
        bf16x8 b1 = load8(&Bs[(wc + 16 + lr) * 32 + lq * 8]);
        acc[0][0] = __builtin_amdgcn_mfma_f32_16x16x32_bf16(a0, b0, acc[0][0], 0, 0, 0);
        acc[0][1] = __builtin_amdgcn_mfma_f32_16x16x32_bf16(a0, b1, acc[0][1], 0, 0, 0);
        acc[1][0] = __builtin_amdgcn_mfma_f32_16x16x32_bf16(a1, b0, acc[1][0], 0, 0, 0);
        acc[1][1] = __builtin_amdgcn_mfma_f32_16x16x32_bf16(a1, b1, acc[1][1], 0, 0, 0);
        __syncthreads();
    }

    #pragma unroll
    for (int r = 0; r < 2; ++r)
        #pragma unroll
        for (int c = 0; c < 2; ++c)
            #pragma unroll
            for (int reg = 0; reg < 4; ++reg) {
                int m = M0 + wr + r * 16 + lq * 4 + reg;
                int n = N0 + wc + c * 16 + lr;
                out[(size_t)m * DIM + n] = acc[r][c][reg] + bias[n];
            }
}

// ---------------------------------------------------------------------------
// Workspace layout (55,050,240 B total -- strictly within the proven
// 55,443,456 B envelope from rounds 2-8):
//   [0, 3sz)          Q | K | Vt   (flash inputs; Q reused as Ab after flash)
//   [3sz, +XSZ*2)     xb           (dead after qkv; Lpart lives at its base)
//   [.., +WQSZ*2)     wqb          (dead after qkv)
//   [.., +WPSZ*2)     wpb          (live until proj)
//   [.., +25.2MB)     Opart fp16   (NSPLIT=4)
// ---------------------------------------------------------------------------
extern "C" void kernel_launch(void* const* d_in, const int* in_sizes, int n_in,
                              void* d_out, int out_size, void* d_ws, size_t ws_size,
                              hipStream_t stream)
{
    const float* x      = (const float*)d_in[0];
    const float* w_qkv  = (const float*)d_in[1];
    const float* w_proj = (const float*)d_in[2];
    const float* b_proj = (const float*)d_in[3];
    float* out = (float*)d_out;

    char* ws = (char*)d_ws;
    const size_t sz = (size_t)NH * NTOK * HD * sizeof(bf16_t);  // 6,291,456 B
    bf16_t*   Q     = (bf16_t*)(ws);
    bf16_t*   K     = (bf16_t*)(ws + sz);
    bf16_t*   Vt    = (bf16_t*)(ws + 2 * sz);
    bf16_t*   xb    = (bf16_t*)(ws + 3 * sz);
    bf16_t*   wqb   = (bf16_t*)(ws + 3 * sz + (size_t)XSZ * 2);
    bf16_t*   wpb   = (bf16_t*)(ws + 3 * sz + (size_t)(XSZ + WQSZ) * 2);
    _Float16* Opart = (_Float16*)(ws + 3 * sz + (size_t)(XSZ + WQSZ + WPSZ) * 2);
    float*    Lpart = (float*)xb;   // xb dead after qkv_gemm; 786,432 B fits
    bf16_t*   Ab    = Q;            // Q dead after flash_attn

    cvt_kernel<<<dim3((XSZ + WQSZ + WPSZ) / 1024), 256, 0, stream>>>(
        x, w_qkv, w_proj, xb, wqb, wpb);
    qkv_gemm_kernel<<<dim3(NTOK / 128, (3 * DIM) / 128), 256, 0, stream>>>(
        xb, wqb, Q, K, Vt);
    flash_attn_kernel<<<dim3(NTOK / 256, NH, NSPLIT), 256, 0, stream>>>(
        Q, K, Vt, Opart, Lpart);
    combine_kernel<<<dim3((NTOK * DIM / 4) / 256), 256, 0, stream>>>(
        Opart, Lpart, Ab);
    proj_gemm_kernel<<<dim3(NTOK / 64, DIM / 64), 256, 0, stream>>>(
        Ab, wpb, b_proj, out);
}

// Round 10
// 209.112 us; speedup vs baseline: 1.1157x; 1.1157x over previous
//
#include <hip/hip_runtime.h>
#include <hip/hip_bf16.h>

typedef __bf16 bf16_t;
typedef __attribute__((ext_vector_type(8))) __bf16 bf16x8;
typedef __attribute__((ext_vector_type(4))) __bf16 bf16x4;
typedef __attribute__((ext_vector_type(4))) short s16x4;
typedef __attribute__((ext_vector_type(4))) float f32x4;
typedef __attribute__((ext_vector_type(4))) _Float16 f16x4;

#define NTOK 4096
#define DIM  768
#define NH   12
#define HD   64
#define NSPLIT 4
#define KHALF (NTOK / NSPLIT)   // 1024 -> NIT=16
#define XSZ  (NTOK * DIM)       // 3,145,728
#define WQSZ (3 * DIM * DIM)    // 1,769,472
#define WPSZ (DIM * DIM)        //   589,824
// 0.125 * log2(e): folded into Q so S^T is directly in log2 domain
#define SCALE_L2E 0.18033688011112042f
// static softmax shift (shift-invariant, no overflow for |st|<~15)
#define SOFTMAX_C 12.0f

__device__ __forceinline__ bf16x8 load8(const bf16_t* p) {
    return *reinterpret_cast<const bf16x8*>(p);
}
__device__ __forceinline__ void store8(bf16_t* p, bf16x8 v) {
    *reinterpret_cast<bf16x8*>(p) = v;
}
// async global->LDS, 16B per lane; LDS dest = wave-uniform base + lane*16
__device__ __forceinline__ void gl2lds16(const bf16_t* g, bf16_t* l) {
    __builtin_amdgcn_global_load_lds(
        (const __attribute__((address_space(1))) void*)g,
        (__attribute__((address_space(3))) void*)l, 16, 0, 0);
}

// ---------------------------------------------------------------------------
// Convert fp32 inputs to bf16 once (memory-bound, ~33 MB total).
// ---------------------------------------------------------------------------
__global__ __launch_bounds__(256) void cvt_kernel(
    const float* __restrict__ x, const float* __restrict__ wq,
    const float* __restrict__ wp,
    bf16_t* __restrict__ xb, bf16_t* __restrict__ wqb, bf16_t* __restrict__ wpb)
{
    size_t i = ((size_t)blockIdx.x * 256 + threadIdx.x) * 4;
    const float* src; bf16_t* dst; size_t off;
    if (i < XSZ)             { src = x;  dst = xb;  off = i; }
    else if (i < XSZ + WQSZ) { src = wq; dst = wqb; off = i - XSZ; }
    else                     { src = wp; dst = wpb; off = i - XSZ - WQSZ; }
    float4 v = *reinterpret_cast<const float4*>(src + off);
    bf16x4 o = { (bf16_t)v.x, (bf16_t)v.y, (bf16_t)v.z, (bf16_t)v.w };
    *reinterpret_cast<bf16x4*>(dst + off) = o;
}

// ---------------------------------------------------------------------------
// QKV GEMM, m97-style: 128x128 tile, BK=32, staging via global_load_lds
// width=16 into CONTIGUOUS [128][32] LDS. 2 barriers per K-step.
// Epilogue scatter: t=0: Q[h][m][d] (*SCALE_L2E)  t=1: K[h][m][d]
//                   t=2: Vt[h][d][m] (8B stores)
// ---------------------------------------------------------------------------
__global__ __launch_bounds__(256) void qkv_gemm_kernel(
    const bf16_t* __restrict__ X, const bf16_t* __restrict__ W,
    bf16_t* __restrict__ Qo, bf16_t* __restrict__ Ko, bf16_t* __restrict__ Vt)
{
    __shared__ __align__(16) bf16_t As[128 * 32];
    __shared__ __align__(16) bf16_t Bs[128 * 32];
    const int tid  = threadIdx.x;
    const int wave = tid >> 6, lane = tid & 63;
    const int lr = lane & 15, lq = lane >> 4;
    const int M0 = blockIdx.x * 128;
    const int N0 = blockIdx.y * 128;
    const int wm = (wave >> 1) * 64, wn = (wave & 1) * 64;

    const int g_row = wave * 32 + (lane >> 2);     // + c*16
    const int g_col = (lane & 3) * 8;

    f32x4 acc[4][4] = {};

    for (int k0 = 0; k0 < DIM; k0 += 32) {
        #pragma unroll
        for (int c = 0; c < 2; ++c) {
            gl2lds16(&X[(size_t)(M0 + g_row + c * 16) * DIM + k0 + g_col],
                     &As[(wave * 32 + c * 16) * 32]);
            gl2lds16(&W[(size_t)(N0 + g_row + c * 16) * DIM + k0 + g_col],
                     &Bs[(wave * 32 + c * 16) * 32]);
        }
        __syncthreads();   // drains vmcnt: LDS tiles complete
        bf16x8 af[4], bfr[4];
        #pragma unroll
        for (int i = 0; i < 4; ++i) af[i]  = load8(&As[(wm + i * 16 + lr) * 32 + lq * 8]);
        #pragma unroll
        for (int i = 0; i < 4; ++i) bfr[i] = load8(&Bs[(wn + i * 16 + lr) * 32 + lq * 8]);
        #pragma unroll
        for (int r = 0; r < 4; ++r)
            #pragma unroll
            for (int c = 0; c < 4; ++c)
                acc[r][c] = __builtin_amdgcn_mfma_f32_16x16x32_bf16(af[r], bfr[c], acc[r][c], 0, 0, 0);
        __syncthreads();   // protect LDS before next overwrite
    }

    const int t = N0 / DIM;      // uniform per block (768 % 128 == 0)
    if (t == 2) {
        #pragma unroll
        for (int r = 0; r < 4; ++r)
            #pragma unroll
            for (int c = 0; c < 4; ++c) {
                int m0 = M0 + wm + r * 16 + lq * 4;
                int rem = N0 + wn + c * 16 + lr - 2 * DIM;
                int hh = rem >> 6, d = rem & 63;
                bf16x4 v = { (bf16_t)acc[r][c][0], (bf16_t)acc[r][c][1],
                             (bf16_t)acc[r][c][2], (bf16_t)acc[r][c][3] };
                *reinterpret_cast<bf16x4*>(&Vt[((size_t)hh * HD + d) * NTOK + m0]) = v;
            }
    } else {
        #pragma unroll
        for (int r = 0; r < 4; ++r)
            #pragma unroll
            for (int c = 0; c < 4; ++c)
                #pragma unroll
                for (int reg = 0; reg < 4; ++reg) {
                    int m = M0 + wm + r * 16 + lq * 4 + reg;
                    int rem = N0 + wn + c * 16 + lr - t * DIM;
                    int hh = rem >> 6, d = rem & 63;
                    float v = acc[r][c][reg];
                    if (t == 0) Qo[(hh * NTOK + m) * HD + d] = (bf16_t)(v * SCALE_L2E);
                    else        Ko[(hh * NTOK + m) * HD + d] = (bf16_t)v;
                }
    }
}

// ---------------------------------------------------------------------------
// Flash attention, S^T form, static-shift softmax, split-K=4.
// 512-thread blocks (8 waves), 32 q-rows/wave (r8 base: 80.9us, VGPR 48).
//
// *** r10: break the read->compute serialization. ***
// r9 falsified "LDS-pipe-bound" (halving LDS bytes made it 1.57x WORSE at
// 1 wave/SIMD). Revised model: wall ~= LDS-work + matrix-work ADDITIVE
// (253 + ~271 CU-cyc per wave-iter ~= measured 192k/384) -- the pipes do
// not overlap because at VGPR=48 the compiler register-minimized into
// read->use->read->use chains (no spare regs to hoist loads). Fixes:
//  (a) group-level software pipeline: K/V fragments for group g+1 load
//      into a register double-buffer BEFORE group g's MFMAs (static cur/nxt
//      under full unroll); compiler's counted lgkmcnt overlaps them.
//  (b) row-sum back on VALU (la +=) instead of ones-MFMA: if x16 MFMAs
//      occupy full matrix slots, 8 slots/iter (~39 CU-cyc) move to the
//      underutilized VALU (~16 SIMD-cyc) and the pack chain shortens.
//
// Counted-vmcnt skeleton from r8 (proven safe): prologue stages tiles 0+1
// then one __syncthreads; loop = compute(buf) -> lgkmcnt(0)+sbar ->
// stage(it+2) -> vmcnt(2) -> sbar. Tail drains vmcnt(0).
//
// XOR-swizzled stride-64 LDS: cell (row, swgroup) holds original column
// group swgroup ^ (row&7). Reads: kc0/kc1, vc[g] lane consts. Staging via
// global_load_lds: LDS dest LINEAR; swizzle in per-lane GLOBAL source col
// (wave w, lane l: row w*8+l/8, src col group (l%8)^(l/8)).
// QK acc init -SOFTMAX_C (sub folded into MFMA C-in).
// NOTE: plain __launch_bounds__(512); (N,waves) hints force arch/acc split
// and spill (r2: 48 VGPR, 432 MB scratch, 242 us).
// ---------------------------------------------------------------------------
__global__ __launch_bounds__(512) void flash_attn_kernel(
    const bf16_t* __restrict__ Qb, const bf16_t* __restrict__ Kb,
    const bf16_t* __restrict__ Vtb, _Float16* __restrict__ Opart,
    float* __restrict__ Lpart)
{
    __shared__ __align__(16) bf16_t Ks[2][64 * 64];   // [key][d]  swizzled
    __shared__ __align__(16) bf16_t Vs[2][64 * 64];   // [d][key]  swizzled
    const int tid  = threadIdx.x;
    const int wave = tid >> 6, lane = tid & 63;       // wave 0..7
    const int lr = lane & 15, lq = lane >> 4;
    const int h  = blockIdx.y;
    const int q0 = blockIdx.x * 256;
    const int sp = blockIdx.z;
    const int kt0 = sp * KHALF;
    const int NIT = KHALF / 64;     // 16

    // read-side swizzle constants (elements) -- unchanged from r3..r9
    const int kc0 = (lq ^ (lr & 7)) * 8;                             // K frag d 0..31
    const int kc1 = ((4 + lq) ^ (lr & 7)) * 8;                       // K frag d 32..63
    int vc[4];
    #pragma unroll
    for (int g = 0; g < 4; ++g)
        vc[g] = ((2 * g + (lq >> 1)) ^ (lr & 7)) * 8 + (lq & 1) * 4; // V frag keys

    // staging: wave w covers rows w*8 .. w*8+8 of the 64-row tile, 1 call
    const int srow = lane >> 3;                        // 0..7
    const int scol = ((lane & 7) ^ srow) * 8;          // inverse-swizzled col
    const bf16_t* kbase = &Kb[(size_t)h * NTOK * HD];
    const bf16_t* vbase = &Vtb[(size_t)h * HD * NTOK];
    const size_t kof = (size_t)(wave * 8 + srow) * HD + scol;
    const size_t vof = (size_t)(wave * 8 + srow) * NTOK + scol;
    const int ldw = (wave * 8) * 64;       // wave-uniform LDS dest (elements)

    // Q as B-operand of S^T for two q-subtiles (rows +lr and +16+lr)
    const bf16_t* qrowA = &Qb[((size_t)h * NTOK + q0 + wave * 32 + lr) * HD];
    const bf16_t* qrowB = qrowA + 16 * HD;
    bf16x8 qa0 = load8(&qrowA[lq * 8]);
    bf16x8 qa1 = load8(&qrowA[32 + lq * 8]);
    bf16x8 qb0 = load8(&qrowB[lq * 8]);
    bf16x8 qb1 = load8(&qrowB[32 + lq * 8]);

    float la = 0.f, lb = 0.f;
    f32x4 oA[4] = {}, oB[4] = {};
    const f32x4 mc = { -SOFTMAX_C, -SOFTMAX_C, -SOFTMAX_C, -SOFTMAX_C };

    // prologue: stage tiles 0 and 1, then ONE full drain
    gl2lds16(kbase + (size_t)kt0 * HD + kof, &Ks[0][ldw]);
    gl2lds16(vbase + kt0 + vof,              &Vs[0][ldw]);
    gl2lds16(kbase + (size_t)(kt0 + 64) * HD + kof, &Ks[1][ldw]);
    gl2lds16(vbase + (kt0 + 64) + vof,              &Vs[1][ldw]);
    __syncthreads();                   // tiles 0 AND 1 resident block-wide

    for (int it = 0; it < NIT; ++it) {
        const int buf = it & 1;
        const bf16_t* Kt = Ks[buf];
        const bf16_t* Vt_ = Vs[buf];

        // register double-buffer of K/V fragments: loads for group g+1
        // issue BEFORE group g's compute (indices static under unroll).
        bf16x8 kf0[2], kf1[2];
        s16x4  vf[2][4];
        kf0[0] = load8(&Kt[lr * 64 + kc0]);
        kf1[0] = load8(&Kt[lr * 64 + kc1]);
        #pragma unroll
        for (int dt = 0; dt < 4; ++dt)
            vf[0][dt] = *reinterpret_cast<const s16x4*>(
                &Vt_[(dt * 16 + lr) * 64 + vc[0]]);

        #pragma unroll
        for (int g = 0; g < 4; ++g) {
            const int cur = g & 1, nxt = cur ^ 1;
            if (g < 3) {   // issue next group's loads now; complete under MFMA
                kf0[nxt] = load8(&Kt[((g + 1) * 16 + lr) * 64 + kc0]);
                kf1[nxt] = load8(&Kt[((g + 1) * 16 + lr) * 64 + kc1]);
                #pragma unroll
                for (int dt = 0; dt < 4; ++dt)
                    vf[nxt][dt] = *reinterpret_cast<const s16x4*>(
                        &Vt_[(dt * 16 + lr) * 64 + vc[g + 1]]);
            }
            f32x4 za = mc, zb = mc;
            __builtin_amdgcn_s_setprio(1);
            za = __builtin_amdgcn_mfma_f32_16x16x32_bf16(kf0[cur], qa0, za, 0, 0, 0);
            za = __builtin_amdgcn_mfma_f32_16x16x32_bf16(kf1[cur], qa1, za, 0, 0, 0);
            zb = __builtin_amdgcn_mfma_f32_16x16x32_bf16(kf0[cur], qb0, zb, 0, 0, 0);
            zb = __builtin_amdgcn_mfma_f32_16x16x32_bf16(kf1[cur], qb1, zb, 0, 0, 0);
            __builtin_amdgcn_s_setprio(0);
            #pragma unroll
            for (int r = 0; r < 4; ++r) {
                za[r] = __builtin_amdgcn_exp2f(za[r]);
                la += za[r];
                zb[r] = __builtin_amdgcn_exp2f(zb[r]);
                lb += zb[r];
            }
            bf16x4 pa = { (bf16_t)za[0], (bf16_t)za[1],
                          (bf16_t)za[2], (bf16_t)za[3] };
            bf16x4 pb = { (bf16_t)zb[0], (bf16_t)zb[1],
                          (bf16_t)zb[2], (bf16_t)zb[3] };
            s16x4 psa = __builtin_bit_cast(s16x4, pa);
            s16x4 psb = __builtin_bit_cast(s16x4, pb);
            __builtin_amdgcn_s_setprio(1);
            #pragma unroll
            for (int dt = 0; dt < 4; ++dt) {
                oA[dt] = __builtin_amdgcn_mfma_f32_16x16x16bf16_1k(vf[cur][dt], psa, oA[dt], 0, 0, 0);
                oB[dt] = __builtin_amdgcn_mfma_f32_16x16x16bf16_1k(vf[cur][dt], psb, oB[dt], 0, 0, 0);
            }
            __builtin_amdgcn_s_setprio(0);
        }

        if (it == NIT - 1) break;      // last tile: no restage, no wait

        // my LDS reads retired -> safe for others to overwrite after barrier
        asm volatile("s_waitcnt lgkmcnt(0)" ::: "memory");
        __builtin_amdgcn_sched_barrier(0);
        __builtin_amdgcn_s_barrier();      // all waves done reading buf

        if (it + 2 < NIT) {
            const int kn = kt0 + (it + 2) * 64;
            gl2lds16(kbase + (size_t)kn * HD + kof, &Ks[buf][ldw]);
            gl2lds16(vbase + kn + vof,              &Vs[buf][ldw]);
            // tile it+1 complete (only the 2 just-issued stay in flight)
            asm volatile("s_waitcnt vmcnt(2)" ::: "memory");
        } else {
            asm volatile("s_waitcnt vmcnt(0)" ::: "memory");  // tail drain
        }
        __builtin_amdgcn_sched_barrier(0);
        __builtin_amdgcn_s_barrier();      // tile it+1 visible block-wide
    }

    la += __shfl_xor(la, 16); la += __shfl_xor(la, 32);
    lb += __shfl_xor(lb, 16); lb += __shfl_xor(lb, 32);
    const int ma = q0 + wave * 32 + lr;
    const int mb = ma + 16;
    if (lq == 0) {
        Lpart[((size_t)sp * NH + h) * NTOK + ma] = la;
        Lpart[((size_t)sp * NH + h) * NTOK + mb] = lb;
    }
    _Float16* oa = &Opart[((size_t)sp * NTOK + ma) * DIM + h * HD];
    _Float16* ob = &Opart[((size_t)sp * NTOK + mb) * DIM + h * HD];
    #pragma unroll
    for (int dt = 0; dt < 4; ++dt) {
        f16x4 va = { (_Float16)oA[dt][0], (_Float16)oA[dt][1],
                     (_Float16)oA[dt][2], (_Float16)oA[dt][3] };
        f16x4 vb = { (_Float16)oB[dt][0], (_Float16)oB[dt][1],
                     (_Float16)oB[dt][2], (_Float16)oB[dt][3] };
        *reinterpret_cast<f16x4*>(&oa[dt * 16 + lq * 4]) = va;
        *reinterpret_cast<f16x4*>(&ob[dt * 16 + lq * 4]) = vb;
    }
}

// ---------------------------------------------------------------------------
// Split-K combine: one pass over the NSPLIT fp16 partials, normalize by the
// summed softmax denominators, emit bf16 A for the proj GEMM.
// ---------------------------------------------------------------------------
__global__ __launch_bounds__(256) void combine_kernel(
    const _Float16* __restrict__ Opart, const float* __restrict__ Lpart,
    bf16_t* __restrict__ Ab)
{
    int idx = blockIdx.x * 256 + threadIdx.x;       // over NTOK*DIM/4
    int m = idx / (DIM / 4);
    int c = (idx - m * (DIM / 4)) * 4;
    int hh = c >> 6;
    float l = 0.f;
    #pragma unroll
    for (int s = 0; s < NSPLIT; ++s)
        l += Lpart[((size_t)s * NH + hh) * NTOK + m];
    float rv = 1.f / l;
    float a0 = 0.f, a1 = 0.f, a2 = 0.f, a3 = 0.f;
    #pragma unroll
    for (int s = 0; s < NSPLIT; ++s) {
        f16x4 v = *reinterpret_cast<const f16x4*>(
            &Opart[((size_t)s * NTOK + m) * DIM + c]);
        a0 += (float)v[0]; a1 += (float)v[1];
        a2 += (float)v[2]; a3 += (float)v[3];
    }
    bf16x4 o = { (bf16_t)(a0 * rv), (bf16_t)(a1 * rv),
                 (bf16_t)(a2 * rv), (bf16_t)(a3 * rv) };
    *reinterpret_cast<bf16x4*>(&Ab[(size_t)m * DIM + c]) = o;
}

// ---------------------------------------------------------------------------
// Proj GEMM: plain bf16 GEMM out = A @ Wp^T + bias, 64x64 tile, BK=32,
// gl2lds16 staging into contiguous [64][32] LDS (bank-uniform for b128
// frag reads).
// ---------------------------------------------------------------------------
__global__ __launch_bounds__(256) void proj_gemm_kernel(
    const bf16_t* __restrict__ A, const bf16_t* __restrict__ W,
    const float* __restrict__ bias, float* __restrict__ out)
{
    __shared__ __align__(16) bf16_t As[64 * 32];
    __shared__ __align__(16) bf16_t Bs[64 * 32];
    const int tid  = threadIdx.x;
    const int wave = tid >> 6, lane = tid & 63;
    const int lr = lane & 15, lq = lane >> 4;
    const int M0 = blockIdx.x * 64;
    const int N0 = blockIdx.y * 64;
    const int wr = (wave >> 1) * 32, wc = (wave & 1) * 32;
    const int g_row = tid >> 2;           // 0..63
    const int g_col = (tid & 3) * 8;

    f32x4 acc[2][2] = {};

    for (int k0 = 0; k0 < DIM; k0 += 32) {
        gl2lds16(&A[(size_t)(M0 + g_row) * DIM + k0 + g_col], &As[wave * 512]);
        gl2lds16(&W[(size_t)(N0 + g_row) * DIM + k0 + g_col], &Bs[wave * 512]);
        __syncthreads();
        bf16x8 a0 = load8(&As[(wr + lr) * 32 + lq * 8]);
        bf16x8 a1 = load8(&As[(wr + 16 + lr) * 32 + lq * 8]);
        bf16x8 b0 = load8(&Bs[(wc + lr) * 32 + lq * 8]);
        bf16x8 b1 = load8(&Bs[(wc + 16 + lr) * 32 + lq * 8]);
        acc[0][0] = __builtin_amdgcn_mfma_f32_16x16x32_bf16(a0, b0, acc[0][0], 0, 0, 0);
        acc[0][1] = __builtin_amdgcn_mfma_f32_16x16x32_bf16(a0, b1, acc[0][1], 0, 0, 0);
        acc[1][0] = __builtin_amdgcn_mfma_f32_16x16x32_bf16(a1, b0, acc[1][0], 0, 0, 0);
        acc[1][1] = __builtin_amdgcn_mfma_f32_16x16x32_bf16(a1, b1, acc[1][1], 0, 0, 0);
        __syncthreads();
    }

    #pragma unroll
    for (int r = 0; r < 2; ++r)
        #pragma unroll
        for (int c = 0; c < 2; ++c)
            #pragma unroll
            for (int reg = 0; reg < 4; ++reg) {
                int m = M0 + wr + r * 16 + lq * 4 + reg;
                int n = N0 + wc + c * 16 + lr;
                out[(size_t)m * DIM + n] = acc[r][c][reg] + bias[n];
            }
}

// ---------------------------------------------------------------------------
// Workspace layout (55,050,240 B total -- strictly within the proven
// 55,443,456 B envelope from rounds 2-9):
//   [0, 3sz)          Q | K | Vt   (flash inputs; Q reused as Ab after flash)
//   [3sz, +XSZ*2)     xb           (dead after qkv; Lpart lives at its base)
//   [.., +WQSZ*2)     wqb          (dead after qkv)
//   [.., +WPSZ*2)     wpb          (live until proj)
//   [.., +25.2MB)     Opart fp16   (NSPLIT=4)
// ---------------------------------------------------------------------------
extern "C" void kernel_launch(void* const* d_in, const int* in_sizes, int n_in,
                              void* d_out, int out_size, void* d_ws, size_t ws_size,
                              hipStream_t stream)
{
    const float* x      = (const float*)d_in[0];
    const float* w_qkv  = (const float*)d_in[1];
    const float* w_proj = (const float*)d_in[2];
    const float* b_proj = (const float*)d_in[3];
    float* out = (float*)d_out;

    char* ws = (char*)d_ws;
    const size_t sz = (size_t)NH * NTOK * HD * sizeof(bf16_t);  // 6,291,456 B
    bf16_t*   Q     = (bf16_t*)(ws);
    bf16_t*   K     = (bf16_t*)(ws + sz);
    bf16_t*   Vt    = (bf16_t*)(ws + 2 * sz);
    bf16_t*   xb    = (bf16_t*)(ws + 3 * sz);
    bf16_t*   wqb   = (bf16_t*)(ws + 3 * sz + (size_t)XSZ * 2);
    bf16_t*   wpb   = (bf16_t*)(ws + 3 * sz + (size_t)(XSZ + WQSZ) * 2);
    _Float16* Opart = (_Float16*)(ws + 3 * sz + (size_t)(XSZ + WQSZ + WPSZ) * 2);
    float*    Lpart = (float*)xb;   // xb dead after qkv_gemm; 786,432 B fits
    bf16_t*   Ab    = Q;            // Q dead after flash_attn

    cvt_kernel<<<dim3((XSZ + WQSZ + WPSZ) / 1024), 256, 0, stream>>>(
        x, w_qkv, w_proj, xb, wqb, wpb);
    qkv_gemm_kernel<<<dim3(NTOK / 128, (3 * DIM) / 128), 256, 0, stream>>>(
        xb, wqb, Q, K, Vt);
    flash_attn_kernel<<<dim3(NTOK / 256, NH, NSPLIT), 512, 0, stream>>>(
        Q, K, Vt, Opart, Lpart);
    combine_kernel<<<dim3((NTOK * DIM / 4) / 256), 256, 0, stream>>>(
        Opart, Lpart, Ab);
    proj_gemm_kernel<<<dim3(NTOK / 64, DIM / 64), 256, 0, stream>>>(
        Ab, wpb, b_proj, out);
}

// Round 11
// 192.787 us; speedup vs baseline: 1.2102x; 1.0847x over previous
//
#include <hip/hip_runtime.h>
#include <hip/hip_bf16.h>

typedef __bf16 bf16_t;
typedef __attribute__((ext_vector_type(8))) __bf16 bf16x8;
typedef __attribute__((ext_vector_type(4))) __bf16 bf16x4;
typedef __attribute__((ext_vector_type(4))) short s16x4;
typedef __attribute__((ext_vector_type(4))) float f32x4;
typedef __attribute__((ext_vector_type(4))) _Float16 f16x4;

#define NTOK 4096
#define DIM  768
#define NH   12
#define HD   64
#define NSPLIT 4
#define KHALF (NTOK / NSPLIT)   // 1024 -> NIT=16
#define XSZ  (NTOK * DIM)       // 3,145,728
#define WQSZ (3 * DIM * DIM)    // 1,769,472
#define WPSZ (DIM * DIM)        //   589,824
// 0.125 * log2(e): folded into Q so S^T is directly in log2 domain
#define SCALE_L2E 0.18033688011112042f
// static softmax shift (shift-invariant, no overflow for |st|<~15)
#define SOFTMAX_C 12.0f

__device__ __forceinline__ bf16x8 load8(const bf16_t* p) {
    return *reinterpret_cast<const bf16x8*>(p);
}
__device__ __forceinline__ void store8(bf16_t* p, bf16x8 v) {
    *reinterpret_cast<bf16x8*>(p) = v;
}
// async global->LDS, 16B per lane; LDS dest = wave-uniform base + lane*16
__device__ __forceinline__ void gl2lds16(const bf16_t* g, bf16_t* l) {
    __builtin_amdgcn_global_load_lds(
        (const __attribute__((address_space(1))) void*)g,
        (__attribute__((address_space(3))) void*)l, 16, 0, 0);
}

// ---------------------------------------------------------------------------
// Convert fp32 inputs to bf16 once (memory-bound, ~33 MB total).
// ---------------------------------------------------------------------------
__global__ __launch_bounds__(256) void cvt_kernel(
    const float* __restrict__ x, const float* __restrict__ wq,
    const float* __restrict__ wp,
    bf16_t* __restrict__ xb, bf16_t* __restrict__ wqb, bf16_t* __restrict__ wpb)
{
    size_t i = ((size_t)blockIdx.x * 256 + threadIdx.x) * 4;
    const float* src; bf16_t* dst; size_t off;
    if (i < XSZ)             { src = x;  dst = xb;  off = i; }
    else if (i < XSZ + WQSZ) { src = wq; dst = wqb; off = i - XSZ; }
    else                     { src = wp; dst = wpb; off = i - XSZ - WQSZ; }
    float4 v = *reinterpret_cast<const float4*>(src + off);
    bf16x4 o = { (bf16_t)v.x, (bf16_t)v.y, (bf16_t)v.z, (bf16_t)v.w };
    *reinterpret_cast<bf16x4*>(dst + off) = o;
}

// ---------------------------------------------------------------------------
// QKV GEMM, m97-style 128x128 tile, BK=32.
// *** r11: LDS double-buffer + stage-ahead (the proven r6 flash pattern). ***
// Old: stage(t) -> sync(full vmcnt drain) -> compute(t) -> sync  == full
// HBM latency (~600-900cyc) serialized into every one of 24 K-steps, twice.
// New: prologue stages tile 0; per step, stage(t+1 -> buf^1) issues BEFORE
// compute(t), ONE __syncthreads per step (its vmcnt drain completes buf^1,
// its lgkmcnt drain retires this wave's frag reads before buf is reused).
// LDS 16->32 KB: still >= 4 blocks/CU. Staging geometry/frag reads unchanged.
// Epilogue scatter: t=0: Q[h][m][d] (*SCALE_L2E)  t=1: K[h][m][d]
//                   t=2: Vt[h][d][m] (8B stores)
// ---------------------------------------------------------------------------
__global__ __launch_bounds__(256) void qkv_gemm_kernel(
    const bf16_t* __restrict__ X, const bf16_t* __restrict__ W,
    bf16_t* __restrict__ Qo, bf16_t* __restrict__ Ko, bf16_t* __restrict__ Vt)
{
    __shared__ __align__(16) bf16_t As[2][128 * 32];
    __shared__ __align__(16) bf16_t Bs[2][128 * 32];
    const int tid  = threadIdx.x;
    const int wave = tid >> 6, lane = tid & 63;
    const int lr = lane & 15, lq = lane >> 4;
    const int M0 = blockIdx.x * 128;
    const int N0 = blockIdx.y * 128;
    const int wm = (wave >> 1) * 64, wn = (wave & 1) * 64;

    const int g_row = wave * 32 + (lane >> 2);     // + c*16
    const int g_col = (lane & 3) * 8;

    f32x4 acc[4][4] = {};

    // prologue: stage K-step 0 into buf 0
    #pragma unroll
    for (int c = 0; c < 2; ++c) {
        gl2lds16(&X[(size_t)(M0 + g_row + c * 16) * DIM + g_col],
                 &As[0][(wave * 32 + c * 16) * 32]);
        gl2lds16(&W[(size_t)(N0 + g_row + c * 16) * DIM + g_col],
                 &Bs[0][(wave * 32 + c * 16) * 32]);
    }
    __syncthreads();

    for (int k0 = 0; k0 < DIM; k0 += 32) {
        const int buf = (k0 >> 5) & 1;
        // stage NEXT K-step into buf^1; completes by the end-of-step barrier
        if (k0 + 32 < DIM) {
            #pragma unroll
            for (int c = 0; c < 2; ++c) {
                gl2lds16(&X[(size_t)(M0 + g_row + c * 16) * DIM + k0 + 32 + g_col],
                         &As[buf ^ 1][(wave * 32 + c * 16) * 32]);
                gl2lds16(&W[(size_t)(N0 + g_row + c * 16) * DIM + k0 + 32 + g_col],
                         &Bs[buf ^ 1][(wave * 32 + c * 16) * 32]);
            }
        }
        bf16x8 af[4], bfr[4];
        #pragma unroll
        for (int i = 0; i < 4; ++i) af[i]  = load8(&As[buf][(wm + i * 16 + lr) * 32 + lq * 8]);
        #pragma unroll
        for (int i = 0; i < 4; ++i) bfr[i] = load8(&Bs[buf][(wn + i * 16 + lr) * 32 + lq * 8]);
        #pragma unroll
        for (int r = 0; r < 4; ++r)
            #pragma unroll
            for (int c = 0; c < 4; ++c)
                acc[r][c] = __builtin_amdgcn_mfma_f32_16x16x32_bf16(af[r], bfr[c], acc[r][c], 0, 0, 0);
        __syncthreads();   // drains vmcnt (buf^1 staged) + lgkm (my reads done)
    }

    const int t = N0 / DIM;      // uniform per block (768 % 128 == 0)
    if (t == 2) {
        #pragma unroll
        for (int r = 0; r < 4; ++r)
            #pragma unroll
            for (int c = 0; c < 4; ++c) {
                int m0 = M0 + wm + r * 16 + lq * 4;
                int rem = N0 + wn + c * 16 + lr - 2 * DIM;
                int hh = rem >> 6, d = rem & 63;
                bf16x4 v = { (bf16_t)acc[r][c][0], (bf16_t)acc[r][c][1],
                             (bf16_t)acc[r][c][2], (bf16_t)acc[r][c][3] };
                *reinterpret_cast<bf16x4*>(&Vt[((size_t)hh * HD + d) * NTOK + m0]) = v;
            }
    } else {
        #pragma unroll
        for (int r = 0; r < 4; ++r)
            #pragma unroll
            for (int c = 0; c < 4; ++c)
                #pragma unroll
                for (int reg = 0; reg < 4; ++reg) {
                    int m = M0 + wm + r * 16 + lq * 4 + reg;
                    int rem = N0 + wn + c * 16 + lr - t * DIM;
                    int hh = rem >> 6, d = rem & 63;
                    float v = acc[r][c][reg];
                    if (t == 0) Qo[(hh * NTOK + m) * HD + d] = (bf16_t)(v * SCALE_L2E);
                    else        Ko[(hh * NTOK + m) * HD + d] = (bf16_t)v;
                }
    }
}

// ---------------------------------------------------------------------------
// Flash attention -- r8 EXACT (80.9us, VGPR 48, passed twice). r9 (qpw=64)
// and r10 (reg dbuf) both regressed via VGPR->residency loss; reverted.
// ---------------------------------------------------------------------------
__global__ __launch_bounds__(512) void flash_attn_kernel(
    const bf16_t* __restrict__ Qb, const bf16_t* __restrict__ Kb,
    const bf16_t* __restrict__ Vtb, _Float16* __restrict__ Opart,
    float* __restrict__ Lpart)
{
    __shared__ __align__(16) bf16_t Ks[2][64 * 64];   // [key][d]  swizzled
    __shared__ __align__(16) bf16_t Vs[2][64 * 64];   // [d][key]  swizzled
    const int tid  = threadIdx.x;
    const int wave = tid >> 6, lane = tid & 63;       // wave 0..7
    const int lr = lane & 15, lq = lane >> 4;
    const int h  = blockIdx.y;
    const int q0 = blockIdx.x * 256;
    const int sp = blockIdx.z;
    const int kt0 = sp * KHALF;
    const int NIT = KHALF / 64;     // 16

    const int kc0 = (lq ^ (lr & 7)) * 8;                             // K frag d 0..31
    const int kc1 = ((4 + lq) ^ (lr & 7)) * 8;                       // K frag d 32..63
    int vc[4];
    #pragma unroll
    for (int g = 0; g < 4; ++g)
        vc[g] = ((2 * g + (lq >> 1)) ^ (lr & 7)) * 8 + (lq & 1) * 4; // V frag keys

    const int srow = lane >> 3;                        // 0..7
    const int scol = ((lane & 7) ^ srow) * 8;          // inverse-swizzled col
    const bf16_t* kbase = &Kb[(size_t)h * NTOK * HD];
    const bf16_t* vbase = &Vtb[(size_t)h * HD * NTOK];
    const size_t kof = (size_t)(wave * 8 + srow) * HD + scol;
    const size_t vof = (size_t)(wave * 8 + srow) * NTOK + scol;
    const int ldw = (wave * 8) * 64;       // wave-uniform LDS dest (elements)

    const bf16_t* qrowA = &Qb[((size_t)h * NTOK + q0 + wave * 32 + lr) * HD];
    const bf16_t* qrowB = qrowA + 16 * HD;
    bf16x8 qa0 = load8(&qrowA[lq * 8]);
    bf16x8 qa1 = load8(&qrowA[32 + lq * 8]);
    bf16x8 qb0 = load8(&qrowB[lq * 8]);
    bf16x8 qb1 = load8(&qrowB[32 + lq * 8]);

    f32x4 oA[4] = {}, oB[4] = {};
    f32x4 lsA = {}, lsB = {};                     // ones-MFMA row-sum acc
    const f32x4 mc = { -SOFTMAX_C, -SOFTMAX_C, -SOFTMAX_C, -SOFTMAX_C };
    const short ONE = (short)0x3F80;              // bf16 1.0
    const s16x4 ones = { ONE, ONE, ONE, ONE };

    // prologue: stage tiles 0 and 1, then ONE full drain
    gl2lds16(kbase + (size_t)kt0 * HD + kof, &Ks[0][ldw]);
    gl2lds16(vbase + kt0 + vof,              &Vs[0][ldw]);
    gl2lds16(kbase + (size_t)(kt0 + 64) * HD + kof, &Ks[1][ldw]);
    gl2lds16(vbase + (kt0 + 64) + vof,              &Vs[1][ldw]);
    __syncthreads();                   // tiles 0 AND 1 resident block-wide

    for (int it = 0; it < NIT; ++it) {
        const int buf = it & 1;

        // fused per key-group: QK -> exp2 -> pack -> PV (+ones row-sum)
        #pragma unroll
        for (int g = 0; g < 4; ++g) {
            bf16x8 k0 = load8(&Ks[buf][(g * 16 + lr) * 64 + kc0]);
            bf16x8 k1 = load8(&Ks[buf][(g * 16 + lr) * 64 + kc1]);
            f32x4 za = mc, zb = mc;
            __builtin_amdgcn_s_setprio(1);
            za = __builtin_amdgcn_mfma_f32_16x16x32_bf16(k0, qa0, za, 0, 0, 0);
            za = __builtin_amdgcn_mfma_f32_16x16x32_bf16(k1, qa1, za, 0, 0, 0);
            zb = __builtin_amdgcn_mfma_f32_16x16x32_bf16(k0, qb0, zb, 0, 0, 0);
            zb = __builtin_amdgcn_mfma_f32_16x16x32_bf16(k1, qb1, zb, 0, 0, 0);
            __builtin_amdgcn_s_setprio(0);
            #pragma unroll
            for (int r = 0; r < 4; ++r) {
                za[r] = __builtin_amdgcn_exp2f(za[r]);
                zb[r] = __builtin_amdgcn_exp2f(zb[r]);
            }
            bf16x4 pa = { (bf16_t)za[0], (bf16_t)za[1],
                          (bf16_t)za[2], (bf16_t)za[3] };
            bf16x4 pb = { (bf16_t)zb[0], (bf16_t)zb[1],
                          (bf16_t)zb[2], (bf16_t)zb[3] };
            s16x4 psa = __builtin_bit_cast(s16x4, pa);
            s16x4 psb = __builtin_bit_cast(s16x4, pb);
            __builtin_amdgcn_s_setprio(1);
            lsA = __builtin_amdgcn_mfma_f32_16x16x16bf16_1k(ones, psa, lsA, 0, 0, 0);
            lsB = __builtin_amdgcn_mfma_f32_16x16x16bf16_1k(ones, psb, lsB, 0, 0, 0);
            #pragma unroll
            for (int dt = 0; dt < 4; ++dt) {
                s16x4 va = *reinterpret_cast<const s16x4*>(
                    &Vs[buf][(dt * 16 + lr) * 64 + vc[g]]);
                oA[dt] = __builtin_amdgcn_mfma_f32_16x16x16bf16_1k(va, psa, oA[dt], 0, 0, 0);
                oB[dt] = __builtin_amdgcn_mfma_f32_16x16x16bf16_1k(va, psb, oB[dt], 0, 0, 0);
            }
            __builtin_amdgcn_s_setprio(0);
        }

        if (it == NIT - 1) break;      // last tile: no restage, no wait

        asm volatile("s_waitcnt lgkmcnt(0)" ::: "memory");
        __builtin_amdgcn_sched_barrier(0);
        __builtin_amdgcn_s_barrier();      // all waves done reading buf

        if (it + 2 < NIT) {
            const int kn = kt0 + (it + 2) * 64;
            gl2lds16(kbase + (size_t)kn * HD + kof, &Ks[buf][ldw]);
            gl2lds16(vbase + kn + vof,              &Vs[buf][ldw]);
            asm volatile("s_waitcnt vmcnt(2)" ::: "memory");
        } else {
            asm volatile("s_waitcnt vmcnt(0)" ::: "memory");  // tail drain
        }
        __builtin_amdgcn_sched_barrier(0);
        __builtin_amdgcn_s_barrier();      // tile it+1 visible block-wide
    }

    const float la = lsA[0], lb = lsB[0];
    const int ma = q0 + wave * 32 + lr;
    const int mb = ma + 16;
    if (lq == 0) {
        Lpart[((size_t)sp * NH + h) * NTOK + ma] = la;
        Lpart[((size_t)sp * NH + h) * NTOK + mb] = lb;
    }
    _Float16* oa = &Opart[((size_t)sp * NTOK + ma) * DIM + h * HD];
    _Float16* ob = &Opart[((size_t)sp * NTOK + mb) * DIM + h * HD];
    #pragma unroll
    for (int dt = 0; dt < 4; ++dt) {
        f16x4 va = { (_Float16)oA[dt][0], (_Float16)oA[dt][1],
                     (_Float16)oA[dt][2], (_Float16)oA[dt][3] };
        f16x4 vb = { (_Float16)oB[dt][0], (_Float16)oB[dt][1],
                     (_Float16)oB[dt][2], (_Float16)oB[dt][3] };
        *reinterpret_cast<f16x4*>(&oa[dt * 16 + lq * 4]) = va;
        *reinterpret_cast<f16x4*>(&ob[dt * 16 + lq * 4]) = vb;
    }
}

// ---------------------------------------------------------------------------
// Split-K combine: one pass over the NSPLIT fp16 partials, normalize by the
// summed softmax denominators, emit bf16 A for the proj GEMM.
// ---------------------------------------------------------------------------
__global__ __launch_bounds__(256) void combine_kernel(
    const _Float16* __restrict__ Opart, const float* __restrict__ Lpart,
    bf16_t* __restrict__ Ab)
{
    int idx = blockIdx.x * 256 + threadIdx.x;       // over NTOK*DIM/4
    int m = idx / (DIM / 4);
    int c = (idx - m * (DIM / 4)) * 4;
    int hh = c >> 6;
    float l = 0.f;
    #pragma unroll
    for (int s = 0; s < NSPLIT; ++s)
        l += Lpart[((size_t)s * NH + hh) * NTOK + m];
    float rv = 1.f / l;
    float a0 = 0.f, a1 = 0.f, a2 = 0.f, a3 = 0.f;
    #pragma unroll
    for (int s = 0; s < NSPLIT; ++s) {
        f16x4 v = *reinterpret_cast<const f16x4*>(
            &Opart[((size_t)s * NTOK + m) * DIM + c]);
        a0 += (float)v[0]; a1 += (float)v[1];
        a2 += (float)v[2]; a3 += (float)v[3];
    }
    bf16x4 o = { (bf16_t)(a0 * rv), (bf16_t)(a1 * rv),
                 (bf16_t)(a2 * rv), (bf16_t)(a3 * rv) };
    *reinterpret_cast<bf16x4*>(&Ab[(size_t)m * DIM + c]) = o;
}

// ---------------------------------------------------------------------------
// Proj GEMM: out = A @ Wp^T + bias, 64x64 tile, BK=32.
// *** r11: same LDS double-buffer + stage-ahead as qkv (one barrier/step,
// HBM staging latency overlaps compute). LDS 8->16 KB, still 5 blocks/CU.
// ---------------------------------------------------------------------------
__global__ __launch_bounds__(256) void proj_gemm_kernel(
    const bf16_t* __restrict__ A, const bf16_t* __restrict__ W,
    const float* __restrict__ bias, float* __restrict__ out)
{
    __shared__ __align__(16) bf16_t As[2][64 * 32];
    __shared__ __align__(16) bf16_t Bs[2][64 * 32];
    const int tid  = threadIdx.x;
    const int wave = tid >> 6, lane = tid & 63;
    const int lr = lane & 15, lq = lane >> 4;
    const int M0 = blockIdx.x * 64;
    const int N0 = blockIdx.y * 64;
    const int wr = (wave >> 1) * 32, wc = (wave & 1) * 32;
    const int g_row = tid >> 2;           // 0..63
    const int g_col = (tid & 3) * 8;

    f32x4 acc[2][2] = {};

    // prologue: stage K-step 0 into buf 0
    gl2lds16(&A[(size_t)(M0 + g_row) * DIM + g_col], &As[0][wave * 512]);
    gl2lds16(&W[(size_t)(N0 + g_row) * DIM + g_col], &Bs[0][wave * 512]);
    __syncthreads();

    for (int k0 = 0; k0 < DIM; k0 += 32) {
        const int buf = (k0 >> 5) & 1;
        if (k0 + 32 < DIM) {
            gl2lds16(&A[(size_t)(M0 + g_row) * DIM + k0 + 32 + g_col],
                     &As[buf ^ 1][wave * 512]);
            gl2lds16(&W[(size_t)(N0 + g_row) * DIM + k0 + 32 + g_col],
                     &Bs[buf ^ 1][wave * 512]);
        }
        bf16x8 a0 = load8(&As[buf][(wr + lr) * 32 + lq * 8]);
        bf16x8 a1 = load8(&As[buf][(wr + 16 + lr) * 32 + lq * 8]);
        bf16x8 b0 = load8(&Bs[buf][(wc + lr) * 32 + lq * 8]);
        bf16x8 b1 = load8(&Bs[buf][(wc + 16 + lr) * 32 + lq * 8]);
        acc[0][0] = __builtin_amdgcn_mfma_f32_16x16x32_bf16(a0, b0, acc[0][0], 0, 0, 0);
        acc[0][1] = __builtin_amdgcn_mfma_f32_16x16x32_bf16(a0, b1, acc[0][1], 0, 0, 0);
        acc[1][0] = __builtin_amdgcn_mfma_f32_16x16x32_bf16(a1, b0, acc[1][0], 0, 0, 0);
        acc[1][1] = __builtin_amdgcn_mfma_f32_16x16x32_bf16(a1, b1, acc[1][1], 0, 0, 0);
        __syncthreads();   // drains vmcnt (buf^1 staged) + lgkm (my reads done)
    }

    #pragma unroll
    for (int r = 0; r < 2; ++r)
        #pragma unroll
        for (int c = 0; c < 2; ++c)
            #pragma unroll
            for (int reg = 0; reg < 4; ++reg) {
                int m = M0 + wr + r * 16 + lq * 4 + reg;
                int n = N0 + wc + c * 16 + lr;
                out[(size_t)m * DIM + n] = acc[r][c][reg] + bias[n];
            }
}

// ---------------------------------------------------------------------------
// Workspace layout (55,050,240 B total -- strictly within the proven
// 55,443,456 B envelope from rounds 2-10):
//   [0, 3sz)          Q | K | Vt   (flash inputs; Q reused as Ab after flash)
//   [3sz, +XSZ*2)     xb           (dead after qkv; Lpart lives at its base)
//   [.., +WQSZ*2)     wqb          (dead after qkv)
//   [.., +WPSZ*2)     wpb          (live until proj)
//   [.., +25.2MB)     Opart fp16   (NSPLIT=4)
// ---------------------------------------------------------------------------
extern "C" void kernel_launch(void* const* d_in, const int* in_sizes, int n_in,
                              void* d_out, int out_size, void* d_ws, size_t ws_size,
                              hipStream_t stream)
{
    const float* x      = (const float*)d_in[0];
    const float* w_qkv  = (const float*)d_in[1];
    const float* w_proj = (const float*)d_in[2];
    const float* b_proj = (const float*)d_in[3];
    float* out = (float*)d_out;

    char* ws = (char*)d_ws;
    const size_t sz = (size_t)NH * NTOK * HD * sizeof(bf16_t);  // 6,291,456 B
    bf16_t*   Q     = (bf16_t*)(ws);
    bf16_t*   K     = (bf16_t*)(ws + sz);
    bf16_t*   Vt    = (bf16_t*)(ws + 2 * sz);
    bf16_t*   xb    = (bf16_t*)(ws + 3 * sz);
    bf16_t*   wqb   = (bf16_t*)(ws + 3 * sz + (size_t)XSZ * 2);
    bf16_t*   wpb   = (bf16_t*)(ws + 3 * sz + (size_t)(XSZ + WQSZ) * 2);
    _Float16* Opart = (_Float16*)(ws + 3 * sz + (size_t)(XSZ + WQSZ + WPSZ) * 2);
    float*    Lpart = (float*)xb;   // xb dead after qkv_gemm; 786,432 B fits
    bf16_t*   Ab    = Q;            // Q dead after flash_attn

    cvt_kernel<<<dim3((XSZ + WQSZ + WPSZ) / 1024), 256, 0, stream>>>(
        x, w_qkv, w_proj, xb, wqb, wpb);
    qkv_gemm_kernel<<<dim3(NTOK / 128, (3 * DIM) / 128), 256, 0, stream>>>(
        xb, wqb, Q, K, Vt);
    flash_attn_kernel<<<dim3(NTOK / 256, NH, NSPLIT), 512, 0, stream>>>(
        Q, K, Vt, Opart, Lpart);
    combine_kernel<<<dim3((NTOK * DIM / 4) / 256), 256, 0, stream>>>(
        Opart, Lpart, Ab);
    proj_gemm_kernel<<<dim3(NTOK / 64, DIM / 64), 256, 0, stream>>>(
        Ab, wpb, b_proj, out);
}

// Round 12
// 189.971 us; speedup vs baseline: 1.2281x; 1.0148x over previous
//
#include <hip/hip_runtime.h>
#include <hip/hip_bf16.h>

typedef __bf16 bf16_t;
typedef __attribute__((ext_vector_type(8))) __bf16 bf16x8;
typedef __attribute__((ext_vector_type(4))) __bf16 bf16x4;
typedef __attribute__((ext_vector_type(4))) short s16x4;
typedef __attribute__((ext_vector_type(4))) float f32x4;
typedef __attribute__((ext_vector_type(16))) float f32x16;
typedef __attribute__((ext_vector_type(4))) _Float16 f16x4;

#define NTOK 4096
#define DIM  768
#define NH   12
#define HD   64
#define NSPLIT 4
#define KHALF (NTOK / NSPLIT)   // 1024 -> NIT=16
#define XSZ  (NTOK * DIM)       // 3,145,728
#define WQSZ (3 * DIM * DIM)    // 1,769,472
#define WPSZ (DIM * DIM)        //   589,824
// 0.125 * log2(e): folded into Q so S^T is directly in log2 domain
#define SCALE_L2E 0.18033688011112042f
// static softmax shift (shift-invariant, no overflow for |st|<~15)
#define SOFTMAX_C 12.0f

__device__ __forceinline__ bf16x8 load8(const bf16_t* p) {
    return *reinterpret_cast<const bf16x8*>(p);
}
__device__ __forceinline__ void store8(bf16_t* p, bf16x8 v) {
    *reinterpret_cast<bf16x8*>(p) = v;
}
// async global->LDS, 16B per lane; LDS dest = wave-uniform base + lane*16
__device__ __forceinline__ void gl2lds16(const bf16_t* g, bf16_t* l) {
    __builtin_amdgcn_global_load_lds(
        (const __attribute__((address_space(1))) void*)g,
        (__attribute__((address_space(3))) void*)l, 16, 0, 0);
}

// ---------------------------------------------------------------------------
// Convert fp32 inputs to bf16 once (memory-bound, ~33 MB total).
// ---------------------------------------------------------------------------
__global__ __launch_bounds__(256) void cvt_kernel(
    const float* __restrict__ x, const float* __restrict__ wq,
    const float* __restrict__ wp,
    bf16_t* __restrict__ xb, bf16_t* __restrict__ wqb, bf16_t* __restrict__ wpb)
{
    size_t i = ((size_t)blockIdx.x * 256 + threadIdx.x) * 4;
    const float* src; bf16_t* dst; size_t off;
    if (i < XSZ)             { src = x;  dst = xb;  off = i; }
    else if (i < XSZ + WQSZ) { src = wq; dst = wqb; off = i - XSZ; }
    else                     { src = wp; dst = wpb; off = i - XSZ - WQSZ; }
    float4 v = *reinterpret_cast<const float4*>(src + off);
    bf16x4 o = { (bf16_t)v.x, (bf16_t)v.y, (bf16_t)v.z, (bf16_t)v.w };
    *reinterpret_cast<bf16x4*>(dst + off) = o;
}

// ---------------------------------------------------------------------------
// QKV GEMM -- r8 EXACT (single-buffered; r11's dbuf version regressed ~6us:
// __syncthreads drains vmcnt(0) anyway, so stage-ahead bought nothing).
// ---------------------------------------------------------------------------
__global__ __launch_bounds__(256) void qkv_gemm_kernel(
    const bf16_t* __restrict__ X, const bf16_t* __restrict__ W,
    bf16_t* __restrict__ Qo, bf16_t* __restrict__ Ko, bf16_t* __restrict__ Vt)
{
    __shared__ __align__(16) bf16_t As[128 * 32];
    __shared__ __align__(16) bf16_t Bs[128 * 32];
    const int tid  = threadIdx.x;
    const int wave = tid >> 6, lane = tid & 63;
    const int lr = lane & 15, lq = lane >> 4;
    const int M0 = blockIdx.x * 128;
    const int N0 = blockIdx.y * 128;
    const int wm = (wave >> 1) * 64, wn = (wave & 1) * 64;

    const int g_row = wave * 32 + (lane >> 2);     // + c*16
    const int g_col = (lane & 3) * 8;

    f32x4 acc[4][4] = {};

    for (int k0 = 0; k0 < DIM; k0 += 32) {
        #pragma unroll
        for (int c = 0; c < 2; ++c) {
            gl2lds16(&X[(size_t)(M0 + g_row + c * 16) * DIM + k0 + g_col],
                     &As[(wave * 32 + c * 16) * 32]);
            gl2lds16(&W[(size_t)(N0 + g_row + c * 16) * DIM + k0 + g_col],
                     &Bs[(wave * 32 + c * 16) * 32]);
        }
        __syncthreads();   // drains vmcnt: LDS tiles complete
        bf16x8 af[4], bfr[4];
        #pragma unroll
        for (int i = 0; i < 4; ++i) af[i]  = load8(&As[(wm + i * 16 + lr) * 32 + lq * 8]);
        #pragma unroll
        for (int i = 0; i < 4; ++i) bfr[i] = load8(&Bs[(wn + i * 16 + lr) * 32 + lq * 8]);
        #pragma unroll
        for (int r = 0; r < 4; ++r)
            #pragma unroll
            for (int c = 0; c < 4; ++c)
                acc[r][c] = __builtin_amdgcn_mfma_f32_16x16x32_bf16(af[r], bfr[c], acc[r][c], 0, 0, 0);
        __syncthreads();   // protect LDS before next overwrite
    }

    const int t = N0 / DIM;      // uniform per block (768 % 128 == 0)
    if (t == 2) {
        #pragma unroll
        for (int r = 0; r < 4; ++r)
            #pragma unroll
            for (int c = 0; c < 4; ++c) {
                int m0 = M0 + wm + r * 16 + lq * 4;
                int rem = N0 + wn + c * 16 + lr - 2 * DIM;
                int hh = rem >> 6, d = rem & 63;
                bf16x4 v = { (bf16_t)acc[r][c][0], (bf16_t)acc[r][c][1],
                             (bf16_t)acc[r][c][2], (bf16_t)acc[r][c][3] };
                *reinterpret_cast<bf16x4*>(&Vt[((size_t)hh * HD + d) * NTOK + m0]) = v;
            }
    } else {
        #pragma unroll
        for (int r = 0; r < 4; ++r)
            #pragma unroll
            for (int c = 0; c < 4; ++c)
                #pragma unroll
                for (int reg = 0; reg < 4; ++reg) {
                    int m = M0 + wm + r * 16 + lq * 4 + reg;
                    int rem = N0 + wn + c * 16 + lr - t * DIM;
                    int hh = rem >> 6, d = rem & 63;
                    float v = acc[r][c][reg];
                    if (t == 0) Qo[(hh * NTOK + m) * HD + d] = (bf16_t)(v * SCALE_L2E);
                    else        Ko[(hh * NTOK + m) * HD + d] = (bf16_t)v;
                }
    }
}

// ---------------------------------------------------------------------------
// Flash attention, S^T form, static-shift softmax, split-K=4.
// 512-thread blocks (8 waves), 32 q-rows/wave. r8 staging/vmcnt skeleton.
//
// *** r12: 32x32 MFMA family -- halve the matrix instruction stream. ***
// All r8-structure variants plateau at 80+-2us with matrix-work (~270cyc,
// 56 MFMAs/wave-iter) additive with the LDS stream (~256cyc). Same FLOPs
// in 24 MFMAs: QK = 8x mfma_f32_32x32x16_bf16 (A=K rows 32 keys, k=d,
// B=Q cols 32 q); PV = 16x mfma_f32_32x32x8bf16_1k.
// Key identity (from the m74/m101-verified 32x32 C/D layout row =
// (reg&3)+8*(reg>>2)+4*(lane>>5)): S-regs z[4o..4o+3] hold keys
// jj+8o+4h exactly = the 32x32x8 B-operand octet k = h*4+jj -- the pack
// is lane-local, no shuffles. V A-frags: b64 at [d][o^(d&7) grp], 16/iter;
// K A-frags: b128, 8/iter -- identical LDS bytes & bank-uniformity to r8.
// Row-sum on VALU into ONE la (q=lane&31); final shfl_xor(32) merges h.
// QK acc init -SOFTMAX_C (folded shift). LDS/swizzle/staging unchanged.
// NOTE: plain __launch_bounds__(512); (N,waves) hints force arch/acc split
// and spill (r2). Watch FETCH: jump over ~55MB = spill (r9/r10 lesson:
// VGPR costs residency; this design targets ~110 arch regs).
// ---------------------------------------------------------------------------
__global__ __launch_bounds__(512) void flash_attn_kernel(
    const bf16_t* __restrict__ Qb, const bf16_t* __restrict__ Kb,
    const bf16_t* __restrict__ Vtb, _Float16* __restrict__ Opart,
    float* __restrict__ Lpart)
{
    __shared__ __align__(16) bf16_t Ks[2][64 * 64];   // [key][d]  swizzled
    __shared__ __align__(16) bf16_t Vs[2][64 * 64];   // [d][key]  swizzled
    const int tid  = threadIdx.x;
    const int wave = tid >> 6, lane = tid & 63;       // wave 0..7
    const int r31 = lane & 31, l5 = lane >> 5, r7 = lane & 7;
    const int h  = blockIdx.y;
    const int q0 = blockIdx.x * 256;
    const int sp = blockIdx.z;
    const int kt0 = sp * KHALF;
    const int NIT = KHALF / 64;     // 16

    // K A-frag col offsets per d-slice s (elements, swizzled):
    //   d = s*16 + l5*8 + j  ->  col-group (s*2+l5) ^ (key&7), key&7 == r7
    int kcol[4];
    #pragma unroll
    for (int s = 0; s < 4; ++s) kcol[s] = ((s * 2 + l5) ^ r7) * 8;
    // V A-frag col offsets per key-octet o: key = o*8 + l5*4 + jj
    int vcol[8];
    #pragma unroll
    for (int o = 0; o < 8; ++o) vcol[o] = (o ^ r7) * 8 + l5 * 4;

    // staging: wave w covers rows w*8 .. w*8+8 of the 64-row tile, 1 call
    const int srow = lane >> 3;                        // 0..7
    const int scol = ((lane & 7) ^ srow) * 8;          // inverse-swizzled col
    const bf16_t* kbase = &Kb[(size_t)h * NTOK * HD];
    const bf16_t* vbase = &Vtb[(size_t)h * HD * NTOK];
    const size_t kof = (size_t)(wave * 8 + srow) * HD + scol;
    const size_t vof = (size_t)(wave * 8 + srow) * NTOK + scol;
    const int ldw = (wave * 8) * 64;       // wave-uniform LDS dest (elements)

    // Q as B-operand (col = q = r31, k = d): 4 d-slices of 16, 8 elems each
    const bf16_t* qrow = &Qb[((size_t)h * NTOK + q0 + wave * 32 + r31) * HD];
    bf16x8 qf[4];
    #pragma unroll
    for (int s = 0; s < 4; ++s) qf[s] = load8(&qrow[s * 16 + l5 * 8]);

    float la = 0.f;
    f32x16 oLo = {}, oHi = {};         // O accum, d 0..31 / 32..63

    // prologue: stage tiles 0 and 1, then ONE full drain
    gl2lds16(kbase + (size_t)kt0 * HD + kof, &Ks[0][ldw]);
    gl2lds16(vbase + kt0 + vof,              &Vs[0][ldw]);
    gl2lds16(kbase + (size_t)(kt0 + 64) * HD + kof, &Ks[1][ldw]);
    gl2lds16(vbase + (kt0 + 64) + vof,              &Vs[1][ldw]);
    __syncthreads();                   // tiles 0 AND 1 resident block-wide

    for (int it = 0; it < NIT; ++it) {
        const int buf = it & 1;
        const bf16_t* Kt = Ks[buf];
        const bf16_t* Vv = Vs[buf];

        // two key-halves: kh=0 -> keys 0..31 (octets 0..3), kh=1 -> 32..63
        #pragma unroll
        for (int kh = 0; kh < 2; ++kh) {
            const int krow = (kh * 32 + r31) * 64;
            f32x16 z;
            #pragma unroll
            for (int r = 0; r < 16; ++r) z[r] = -SOFTMAX_C;
            __builtin_amdgcn_s_setprio(1);
            #pragma unroll
            for (int s = 0; s < 4; ++s) {
                bf16x8 kf = load8(&Kt[krow + kcol[s]]);
                z = __builtin_amdgcn_mfma_f32_32x32x16_bf16(kf, qf[s], z, 0, 0, 0);
            }
            __builtin_amdgcn_s_setprio(0);
            #pragma unroll
            for (int r = 0; r < 16; ++r) {
                z[r] = __builtin_amdgcn_exp2f(z[r]);
                la += z[r];
            }
            __builtin_amdgcn_s_setprio(1);
            #pragma unroll
            for (int o = 0; o < 4; ++o) {
                bf16x4 p = { (bf16_t)z[4 * o], (bf16_t)z[4 * o + 1],
                             (bf16_t)z[4 * o + 2], (bf16_t)z[4 * o + 3] };
                s16x4 ps = __builtin_bit_cast(s16x4, p);
                s16x4 vLo = *reinterpret_cast<const s16x4*>(
                    &Vv[r31 * 64 + vcol[kh * 4 + o]]);
                s16x4 vHi = *reinterpret_cast<const s16x4*>(
                    &Vv[(32 + r31) * 64 + vcol[kh * 4 + o]]);
                oLo = __builtin_amdgcn_mfma_f32_32x32x8bf16_1k(vLo, ps, oLo, 0, 0, 0);
                oHi = __builtin_amdgcn_mfma_f32_32x32x8bf16_1k(vHi, ps, oHi, 0, 0, 0);
            }
            __builtin_amdgcn_s_setprio(0);
        }

        if (it == NIT - 1) break;      // last tile: no restage, no wait

        // my LDS reads retired -> safe for others to overwrite after barrier
        asm volatile("s_waitcnt lgkmcnt(0)" ::: "memory");
        __builtin_amdgcn_sched_barrier(0);
        __builtin_amdgcn_s_barrier();      // all waves done reading buf

        if (it + 2 < NIT) {
            const int kn = kt0 + (it + 2) * 64;
            gl2lds16(kbase + (size_t)kn * HD + kof, &Ks[buf][ldw]);
            gl2lds16(vbase + kn + vof,              &Vs[buf][ldw]);
            // tile it+1 complete (only the 2 just-issued stay in flight)
            asm volatile("s_waitcnt vmcnt(2)" ::: "memory");
        } else {
            asm volatile("s_waitcnt vmcnt(0)" ::: "memory");  // tail drain
        }
        __builtin_amdgcn_sched_barrier(0);
        __builtin_amdgcn_s_barrier();      // tile it+1 visible block-wide
    }

    // merge the two lane-halves' key partial sums (same q col)
    la += __shfl_xor(la, 32);
    const int m = q0 + wave * 32 + r31;
    if (l5 == 0)
        Lpart[((size_t)sp * NH + h) * NTOK + m] = la;

    // O store: C row = (reg&3) + 8*(reg>>2) + 4*l5 -> regs 4t..4t+3 give
    // d = 8t + 4*l5 + {0..3} consecutive (oHi at d+32).
    _Float16* op = &Opart[((size_t)sp * NTOK + m) * DIM + h * HD];
    #pragma unroll
    for (int t = 0; t < 4; ++t) {
        const int d0 = 8 * t + 4 * l5;
        f16x4 vlo = { (_Float16)oLo[4 * t],     (_Float16)oLo[4 * t + 1],
                      (_Float16)oLo[4 * t + 2], (_Float16)oLo[4 * t + 3] };
        f16x4 vhi = { (_Float16)oHi[4 * t],     (_Float16)oHi[4 * t + 1],
                      (_Float16)oHi[4 * t + 2], (_Float16)oHi[4 * t + 3] };
        *reinterpret_cast<f16x4*>(&op[d0])      = vlo;
        *reinterpret_cast<f16x4*>(&op[32 + d0]) = vhi;
    }
}

// ---------------------------------------------------------------------------
// Split-K combine: one pass over the NSPLIT fp16 partials, normalize by the
// summed softmax denominators, emit bf16 A for the proj GEMM.
// ---------------------------------------------------------------------------
__global__ __launch_bounds__(256) void combine_kernel(
    const _Float16* __restrict__ Opart, const float* __restrict__ Lpart,
    bf16_t* __restrict__ Ab)
{
    int idx = blockIdx.x * 256 + threadIdx.x;       // over NTOK*DIM/4
    int m = idx / (DIM / 4);
    int c = (idx - m * (DIM / 4)) * 4;
    int hh = c >> 6;
    float l = 0.f;
    #pragma unroll
    for (int s = 0; s < NSPLIT; ++s)
        l += Lpart[((size_t)s * NH + hh) * NTOK + m];
    float rv = 1.f / l;
    float a0 = 0.f, a1 = 0.f, a2 = 0.f, a3 = 0.f;
    #pragma unroll
    for (int s = 0; s < NSPLIT; ++s) {
        f16x4 v = *reinterpret_cast<const f16x4*>(
            &Opart[((size_t)s * NTOK + m) * DIM + c]);
        a0 += (float)v[0]; a1 += (float)v[1];
        a2 += (float)v[2]; a3 += (float)v[3];
    }
    bf16x4 o = { (bf16_t)(a0 * rv), (bf16_t)(a1 * rv),
                 (bf16_t)(a2 * rv), (bf16_t)(a3 * rv) };
    *reinterpret_cast<bf16x4*>(&Ab[(size_t)m * DIM + c]) = o;
}

// ---------------------------------------------------------------------------
// Proj GEMM -- r8 EXACT (single-buffered; r11 dbuf regressed).
// ---------------------------------------------------------------------------
__global__ __launch_bounds__(256) void proj_gemm_kernel(
    const bf16_t* __restrict__ A, const bf16_t* __restrict__ W,
    const float* __restrict__ bias, float* __restrict__ out)
{
    __shared__ __align__(16) bf16_t As[64 * 32];
    __shared__ __align__(16) bf16_t Bs[64 * 32];
    const int tid  = threadIdx.x;
    const int wave = tid >> 6, lane = tid & 63;
    const int lr = lane & 15, lq = lane >> 4;
    const int M0 = blockIdx.x * 64;
    const int N0 = blockIdx.y * 64;
    const int wr = (wave >> 1) * 32, wc = (wave & 1) * 32;
    const int g_row = tid >> 2;           // 0..63
    const int g_col = (tid & 3) * 8;

    f32x4 acc[2][2] = {};

    for (int k0 = 0; k0 < DIM; k0 += 32) {
        gl2lds16(&A[(size_t)(M0 + g_row) * DIM + k0 + g_col], &As[wave * 512]);
        gl2lds16(&W[(size_t)(N0 + g_row) * DIM + k0 + g_col], &Bs[wave * 512]);
        __syncthreads();
        bf16x8 a0 = load8(&As[(wr + lr) * 32 + lq * 8]);
        bf16x8 a1 = load8(&As[(wr + 16 + lr) * 32 + lq * 8]);
        bf16x8 b0 = load8(&Bs[(wc + lr) * 32 + lq * 8]);
        bf16x8 b1 = load8(&Bs[(wc + 16 + lr) * 32 + lq * 8]);
        acc[0][0] = __builtin_amdgcn_mfma_f32_16x16x32_bf16(a0, b0, acc[0][0], 0, 0, 0);
        acc[0][1] = __builtin_amdgcn_mfma_f32_16x16x32_bf16(a0, b1, acc[0][1], 0, 0, 0);
        acc[1][0] = __builtin_amdgcn_mfma_f32_16x16x32_bf16(a1, b0, acc[1][0], 0, 0, 0);
        acc[1][1] = __builtin_amdgcn_mfma_f32_16x16x32_bf16(a1, b1, acc[1][1], 0, 0, 0);
        __syncthreads();
    }

    #pragma unroll
    for (int r = 0; r < 2; ++r)
        #pragma unroll
        for (int c = 0; c < 2; ++c)
            #pragma unroll
            for (int reg = 0; reg < 4; ++reg) {
                int m = M0 + wr + r * 16 + lq * 4 + reg;
                int n = N0 + wc + c * 16 + lr;
                out[(size_t)m * DIM + n] = acc[r][c][reg] + bias[n];
            }
}

// ---------------------------------------------------------------------------
// Workspace layout (55,050,240 B total -- strictly within the proven
// 55,443,456 B envelope from rounds 2-11):
//   [0, 3sz)          Q | K | Vt   (flash inputs; Q reused as Ab after flash)
//   [3sz, +XSZ*2)     xb           (dead after qkv; Lpart lives at its base)
//   [.., +WQSZ*2)     wqb          (dead after qkv)
//   [.., +WPSZ*2)     wpb          (live until proj)
//   [.., +25.2MB)     Opart fp16   (NSPLIT=4)
// ---------------------------------------------------------------------------
extern "C" void kernel_launch(void* const* d_in, const int* in_sizes, int n_in,
                              void* d_out, int out_size, void* d_ws, size_t ws_size,
                              hipStream_t stream)
{
    const float* x      = (const float*)d_in[0];
    const float* w_qkv  = (const float*)d_in[1];
    const float* w_proj = (const float*)d_in[2];
    const float* b_proj = (const float*)d_in[3];
    float* out = (float*)d_out;

    char* ws = (char*)d_ws;
    const size_t sz = (size_t)NH * NTOK * HD * sizeof(bf16_t);  // 6,291,456 B
    bf16_t*   Q     = (bf16_t*)(ws);
    bf16_t*   K     = (bf16_t*)(ws + sz);
    bf16_t*   Vt    = (bf16_t*)(ws + 2 * sz);
    bf16_t*   xb    = (bf16_t*)(ws + 3 * sz);
    bf16_t*   wqb   = (bf16_t*)(ws + 3 * sz + (size_t)XSZ * 2);
    bf16_t*   wpb   = (bf16_t*)(ws + 3 * sz + (size_t)(XSZ + WQSZ) * 2);
    _Float16* Opart = (_Float16*)(ws + 3 * sz + (size_t)(XSZ + WQSZ + WPSZ) * 2);
    float*    Lpart = (float*)xb;   // xb dead after qkv_gemm; 786,432 B fits
    bf16_t*   Ab    = Q;            // Q dead after flash_attn

    cvt_kernel<<<dim3((XSZ + WQSZ + WPSZ) / 1024), 256, 0, stream>>>(
        x, w_qkv, w_proj, xb, wqb, wpb);
    qkv_gemm_kernel<<<dim3(NTOK / 128, (3 * DIM) / 128), 256, 0, stream>>>(
        xb, wqb, Q, K, Vt);
    flash_attn_kernel<<<dim3(NTOK / 256, NH, NSPLIT), 512, 0, stream>>>(
        Q, K, Vt, Opart, Lpart);
    combine_kernel<<<dim3((NTOK * DIM / 4) / 256), 256, 0, stream>>>(
        Opart, Lpart, Ab);
    proj_gemm_kernel<<<dim3(NTOK / 64, DIM / 64), 256, 0, stream>>>(
        Ab, wpb, b_proj, out);
}